// Round 8
// baseline (460.720 us; speedup 1.0000x reference)
//
#include <hip/hip_runtime.h>
#include <hip/hip_bf16.h>

#define NN 50000
#define EE 640000
#define HC 128
#define NB1 196   // ceil(NN/256)

typedef short bf16x8 __attribute__((ext_vector_type(8)));
typedef float f32x4 __attribute__((ext_vector_type(4)));
typedef unsigned short u16;

__device__ __forceinline__ u16 f2b(float f) {   // RN-even
    unsigned u = __float_as_uint(f);
    unsigned r = u + 0x7FFFu + ((u >> 16) & 1u);
    return (u16)(r >> 16);
}
__device__ __forceinline__ float b2f(u16 h) {
    return __uint_as_float(((unsigned)h) << 16);
}

__device__ __forceinline__ void gload_lds16(const void* g, void* l) {
    __builtin_amdgcn_global_load_lds((const __attribute__((address_space(1))) void*)g,
                                     (__attribute__((address_space(3))) void*)l, 16, 0, 0);
}

// sum across each 16-lane row, all lanes get result: pure DPP (no LDS op)
__device__ __forceinline__ float red16(float x) {
    x += __int_as_float(__builtin_amdgcn_update_dpp(0, __float_as_int(x), 0xB1, 0xF, 0xF, true));
    x += __int_as_float(__builtin_amdgcn_update_dpp(0, __float_as_int(x), 0x4E, 0xF, 0xF, true));
    x += __int_as_float(__builtin_amdgcn_update_dpp(0, __float_as_int(x), 0x141, 0xF, 0xF, true));
    x += __int_as_float(__builtin_amdgcn_update_dpp(0, __float_as_int(x), 0x128, 0xF, 0xF, true));
    return x;
}

// ---------------- CSR build ----------------

__global__ void k_count(const int* __restrict__ ei, int* __restrict__ cnt) {
    int e = blockIdx.x * blockDim.x + threadIdx.x;
    if (e < EE) atomicAdd(&cnt[ei[EE + e]], 1);
}

__global__ void k_bsum(const int* __restrict__ cnt, int* __restrict__ bsum) {
    __shared__ int sd[256];
    int b = blockIdx.x, t = threadIdx.x, i = b * 256 + t;
    sd[t] = (i < NN) ? cnt[i] + 1 : 0;
    __syncthreads();
    for (int o = 128; o; o >>= 1) { if (t < o) sd[t] += sd[t + o]; __syncthreads(); }
    if (!t) bsum[b] = sd[0];
}

// offs + block-scan-of-bsum + self-loop + cursor init, all fused (cursor aliases cnt)
__global__ void k_offs(const int* __restrict__ cnt_in, const int* __restrict__ bsum,
                       int* __restrict__ offs, int* __restrict__ cursor,
                       int* __restrict__ csr) {
    __shared__ int sb[256];
    __shared__ int sd[256];
    int b = blockIdx.x, t = threadIdx.x, i = b * 256 + t;
    sb[t] = (t < NB1) ? bsum[t] : 0;
    int v = (i < NN) ? cnt_in[i] + 1 : 0;
    sd[t] = v;
    __syncthreads();
    for (int o = 1; o < 256; o <<= 1) {
        int u1 = (t >= o) ? sd[t - o] : 0;
        int u2 = (t >= o) ? sb[t - o] : 0;
        __syncthreads();
        sd[t] += u1; sb[t] += u2;
        __syncthreads();
    }
    int bex = (b > 0) ? sb[b - 1] : 0;
    if (i < NN) {
        int o = bex + sd[t] - v;
        offs[i] = o;
        csr[o] = i;          // self loop first
        cursor[i] = o + 1;
    }
    if (b == NB1 - 1 && t == 0) offs[NN] = sb[NB1 - 1];
}

__global__ void k_fill(const int* __restrict__ ei, int* __restrict__ cursor,
                       int* __restrict__ csr) {
    int e = blockIdx.x * blockDim.x + threadIdx.x;
    if (e < EE) {
        int s = ei[e], d = ei[EE + e];
        int pos = atomicAdd(&cursor[d], 1);
        csr[pos] = s;
    }
}

// ---------------- all-layer W cast+transpose ----------------

#define WT_L0 196608              // 256*768
#define WT_LX 32768               // 256*128
#define WT_TOT (WT_L0 + 3 * WT_LX)

__global__ void k_castw_all(const float* __restrict__ Wl1, const float* __restrict__ Wr1,
                            const float* __restrict__ Wl2, const float* __restrict__ Wr2,
                            const float* __restrict__ Wl3, const float* __restrict__ Wr3,
                            const float* __restrict__ Wl4, const float* __restrict__ Wr4,
                            u16* __restrict__ WtAll) {
    int gid = blockIdx.x * 256 + threadIdx.x;
    if (gid >= WT_TOT) return;
    const float *Wl, *Wr;
    int idx, K, base;
    if (gid < WT_L0) { Wl = Wl1; Wr = Wr1; idx = gid; K = 768; base = 0; }
    else {
        int r = gid - WT_L0;
        int l = r >> 15; idx = r & (WT_LX - 1); K = 128; base = WT_L0 + l * WT_LX;
        if (l == 0)      { Wl = Wl2; Wr = Wr2; }
        else if (l == 1) { Wl = Wl3; Wr = Wr3; }
        else             { Wl = Wl4; Wr = Wr4; }
    }
    int c = idx / K, k = idx - c * K;
    float v = (c < 128) ? Wl[k * 128 + c] : Wr[k * 128 + (c - 128)];
    WtAll[base + idx] = f2b(v);
}

// ---------------- MFMA bf16 GEMM (round-6 measured-best structure) ----------------
// xb[N][256] = A[N,K] @ Wt^T (bf16 out). Tile 128 rows x 256 cols, 8 waves (2x4, 64x64 each),
// BK=64, 512 threads. LDS: As[128][64] (16KB) + Bs[256][64] (32KB) = 48KB.
// 16B-chunk XOR swizzle phys = logical ^ (row&7); pre-swizzled global source, linear LDS dest.

template<int K, bool F32A>
__global__ __launch_bounds__(512, 4)
void k_gemm(const void* __restrict__ Ag, const u16* __restrict__ Wt,
            u16* __restrict__ xb) {
    __shared__ __align__(16) u16 As[128 * 64];
    __shared__ __align__(16) u16 Bs[256 * 64];
    const int tid = threadIdx.x;
    const int wv = tid >> 6, ln = tid & 63;
    const int wr = wv >> 2, wc = wv & 3;
    const int m0 = blockIdx.x * 128;
    const int lrow = ln & 15, g = ln >> 4;

    f32x4 acc[4][4] = {};

    const float* Af = (const float*)Ag;
    const u16* Ab = (const u16*)Ag;
    const int arow = tid >> 2, aq = tid & 3;   // 512 thr -> arow 0..127
    int arg = m0 + arow; if (arg >= NN) arg = 0;
    float4 ra0, ra1, ra2, ra3;

    if constexpr (F32A) {
        const float* src = Af + (size_t)arg * K + aq * 16;
        ra0 = *(const float4*)(src);
        ra1 = *(const float4*)(src + 4);
        ra2 = *(const float4*)(src + 8);
        ra3 = *(const float4*)(src + 12);
    }

    constexpr int NSTEP = K / 64;
    for (int ks = 0; ks < NSTEP; ++ks) {
        if constexpr (F32A) {
            const int s = arow & 7;
            bf16x8 v0, v1;
            v0[0] = (short)f2b(ra0.x); v0[1] = (short)f2b(ra0.y);
            v0[2] = (short)f2b(ra0.z); v0[3] = (short)f2b(ra0.w);
            v0[4] = (short)f2b(ra1.x); v0[5] = (short)f2b(ra1.y);
            v0[6] = (short)f2b(ra1.z); v0[7] = (short)f2b(ra1.w);
            v1[0] = (short)f2b(ra2.x); v1[1] = (short)f2b(ra2.y);
            v1[2] = (short)f2b(ra2.z); v1[3] = (short)f2b(ra2.w);
            v1[4] = (short)f2b(ra3.x); v1[5] = (short)f2b(ra3.y);
            v1[6] = (short)f2b(ra3.z); v1[7] = (short)f2b(ra3.w);
            *(bf16x8*)&As[arow * 64 + (((aq * 2) ^ s) * 8)] = v0;
            *(bf16x8*)&As[arow * 64 + (((aq * 2 + 1) ^ s) * 8)] = v1;
        } else {
            #pragma unroll
            for (int q = 0; q < 2; ++q) {
                int r8 = (wv * 2 + q) * 8;          // 16 segs x 8 rows = 128
                int row = r8 + (ln >> 3);
                int lc = (ln & 7) ^ (row & 7);
                int rg = m0 + row; if (rg >= NN) rg = 0;
                gload_lds16(Ab + (size_t)rg * K + ks * 64 + lc * 8, &As[r8 * 64]);
            }
        }
        #pragma unroll
        for (int q = 0; q < 4; ++q) {
            int r8 = (wv * 4 + q) * 8;              // 32 segs x 8 rows = 256
            int row = r8 + (ln >> 3);
            int lc = (ln & 7) ^ (row & 7);
            gload_lds16(Wt + (size_t)row * K + ks * 64 + lc * 8, &Bs[r8 * 64]);
        }
        __syncthreads();   // drains vmcnt (gload_lds) + lgkmcnt (ds_write)

        if constexpr (F32A) {
            if (ks + 1 < NSTEP) {   // T14: issue next tile's loads, consume after next barrier
                const float* src = Af + (size_t)arg * K + (ks + 1) * 64 + aq * 16;
                ra0 = *(const float4*)(src);
                ra1 = *(const float4*)(src + 4);
                ra2 = *(const float4*)(src + 8);
                ra3 = *(const float4*)(src + 12);
            }
        }

        #pragma unroll
        for (int kk = 0; kk < 2; ++kk) {
            bf16x8 af[4], bfr[4];
            #pragma unroll
            for (int f = 0; f < 4; ++f) {
                int r = wr * 64 + f * 16 + lrow;
                af[f] = *(const bf16x8*)&As[r * 64 + (((kk * 4 + g) ^ (r & 7)) * 8)];
                int c = wc * 64 + f * 16 + lrow;
                bfr[f] = *(const bf16x8*)&Bs[c * 64 + (((kk * 4 + g) ^ (c & 7)) * 8)];
            }
            #pragma unroll
            for (int i = 0; i < 4; ++i)
                #pragma unroll
                for (int j = 0; j < 4; ++j)
                    acc[i][j] = __builtin_amdgcn_mfma_f32_16x16x32_bf16(af[i], bfr[j], acc[i][j], 0, 0, 0);
        }
        __syncthreads();
    }

    const int crow0 = m0 + wr * 64 + (g << 2);
    const int ccol0 = wc * 64 + lrow;
    #pragma unroll
    for (int i = 0; i < 4; ++i)
        #pragma unroll
        for (int rr = 0; rr < 4; ++rr) {
            int row = crow0 + i * 16 + rr;
            if (row < NN) {
                #pragma unroll
                for (int j = 0; j < 4; ++j)
                    xb[(size_t)row * 256 + ccol0 + j * 16] = f2b(acc[i][j][rr]);
            }
        }
}

// ---------------- per-node online-softmax GATv2 aggregation ----------------
// ONE WAVE per node; lane ln owns channel pair ch0 = (ln>>4)*32 + (ln&15)*2.
// Indices loaded 64-wide coalesced, broadcast via __shfl.
// 8 independent gather/softmax streams, fully predicated 8-wide batches (wave-uniform ok,
// no divergent tail; out-of-range lanes clamp to self row = cache-hot).

__global__ __launch_bounds__(256)
void k_edge(const u16* __restrict__ xb, const float* __restrict__ att,
            const float* __restrict__ bias, const int* __restrict__ offs,
            const int* __restrict__ csr, u16* __restrict__ outb,
            float* __restrict__ outf, int relu) {
    int i = blockIdx.x * 4 + (threadIdx.x >> 6);
    if (i >= NN) return;
    int ln = threadIdx.x & 63;
    int ch0 = ((ln >> 4) << 5) + ((ln & 15) << 1);

    unsigned xr2 = *(const unsigned*)&xb[(size_t)i * 256 + 128 + ch0];
    float xri0 = b2f((u16)xr2), xri1 = b2f((u16)(xr2 >> 16));
    float2 atv = *(const float2*)&att[ch0];
    const float at0 = atv.x, at1 = atv.y;
    int beg = offs[i];
    int deg = offs[i + 1] - beg;

    float m0v = -3.0e38f, s0v = 0.f, p00 = 0.f, p01 = 0.f;
    float m1v = -3.0e38f, s1v = 0.f, p10 = 0.f, p11 = 0.f;
    float m2v = -3.0e38f, s2v = 0.f, p20 = 0.f, p21 = 0.f;
    float m3v = -3.0e38f, s3v = 0.f, p30 = 0.f, p31 = 0.f;
    float m4v = -3.0e38f, s4v = 0.f, p40 = 0.f, p41 = 0.f;
    float m5v = -3.0e38f, s5v = 0.f, p50 = 0.f, p51 = 0.f;
    float m6v = -3.0e38f, s6v = 0.f, p60 = 0.f, p61 = 0.f;
    float m7v = -3.0e38f, s7v = 0.f, p70 = 0.f, p71 = 0.f;

#define GATH(k, jj) unsigned w##k = *(const unsigned*)&xb[(size_t)(jj) * 256 + ch0];
#define UPD(k, M, S, A0, A1, ok) { \
    float v0 = b2f((u16)w##k), v1 = b2f((u16)(w##k >> 16)); \
    float u0 = v0 + xri0; u0 = fmaxf(u0, 0.2f * u0); \
    float u1 = v1 + xri1; u1 = fmaxf(u1, 0.2f * u1); \
    float e = red16(u0 * at0 + u1 * at1); \
    float d = e - M; \
    float tt = __expf(-fabsf(d)); \
    bool ng = (d <= 0.f) || (!(ok)); \
    float c = ng ? 1.f : tt; \
    float ww = (ok) ? (ng ? tt : 1.f) : 0.f; \
    M = ng ? M : e; \
    S = S * c + ww; A0 = A0 * c + ww * v0; A1 = A1 * c + ww * v1; }

    for (int base = 0; base < deg; base += 64) {
        int lim = deg - base; if (lim > 64) lim = 64;
        int idxv = (base + ln < deg) ? csr[beg + base + ln] : i;
        for (int p = 0; p < lim; p += 8) {
            int j0 = __shfl(idxv, p + 0);
            int j1 = __shfl(idxv, p + 1);
            int j2 = __shfl(idxv, p + 2);
            int j3 = __shfl(idxv, p + 3);
            int j4 = __shfl(idxv, p + 4);
            int j5 = __shfl(idxv, p + 5);
            int j6 = __shfl(idxv, p + 6);
            int j7 = __shfl(idxv, p + 7);
            GATH(0, j0) GATH(1, j1) GATH(2, j2) GATH(3, j3)
            GATH(4, j4) GATH(5, j5) GATH(6, j6) GATH(7, j7)
            UPD(0, m0v, s0v, p00, p01, true)
            UPD(1, m1v, s1v, p10, p11, (p + 1 < lim))
            UPD(2, m2v, s2v, p20, p21, (p + 2 < lim))
            UPD(3, m3v, s3v, p30, p31, (p + 3 < lim))
            UPD(4, m4v, s4v, p40, p41, (p + 4 < lim))
            UPD(5, m5v, s5v, p50, p51, (p + 5 < lim))
            UPD(6, m6v, s6v, p60, p61, (p + 6 < lim))
            UPD(7, m7v, s7v, p70, p71, (p + 7 < lim))
        }
    }
#undef GATH
#undef UPD

    float mm = fmaxf(fmaxf(fmaxf(m0v, m1v), fmaxf(m2v, m3v)),
                     fmaxf(fmaxf(m4v, m5v), fmaxf(m6v, m7v)));
    float c0 = __expf(m0v - mm), c1 = __expf(m1v - mm);
    float c2 = __expf(m2v - mm), c3 = __expf(m3v - mm);
    float c4 = __expf(m4v - mm), c5 = __expf(m5v - mm);
    float c6 = __expf(m6v - mm), c7 = __expf(m7v - mm);
    float s = s0v * c0 + s1v * c1 + s2v * c2 + s3v * c3
            + s4v * c4 + s5v * c5 + s6v * c6 + s7v * c7 + 1e-16f;
    float inv = 1.f / s;
    float2 bv = *(const float2*)&bias[ch0];
    float o0 = (p00 * c0 + p10 * c1 + p20 * c2 + p30 * c3
              + p40 * c4 + p50 * c5 + p60 * c6 + p70 * c7) * inv + bv.x;
    float o1 = (p01 * c0 + p11 * c1 + p21 * c2 + p31 * c3
              + p41 * c4 + p51 * c5 + p61 * c6 + p71 * c7) * inv + bv.y;
    if (relu) { o0 = fmaxf(o0, 0.f); o1 = fmaxf(o1, 0.f); }
    if (outb) {
        unsigned pk = (unsigned)f2b(o0) | ((unsigned)f2b(o1) << 16);
        *(unsigned*)&outb[(size_t)i * HC + ch0] = pk;
    }
    if (outf) {
        *(float2*)&outf[(size_t)i * HC + ch0] = make_float2(o0, o1);
    }
}

// ---------------- tail ----------------

__global__ __launch_bounds__(256)
void k_colsum(const float* __restrict__ h, float* __restrict__ gsum) {
    __shared__ float4 sd[8][32];
    int t = threadIdx.x;
    int c4 = t & 31, rl = t >> 5;
    float sx = 0.f, sy = 0.f, sz = 0.f, sw = 0.f;
    for (int r = blockIdx.x * 8 + rl; r < NN; r += 8 * gridDim.x) {
        float4 v = *(const float4*)&h[(size_t)r * HC + c4 * 4];
        sx += v.x; sy += v.y; sz += v.z; sw += v.w;
    }
    sd[rl][c4] = make_float4(sx, sy, sz, sw);
    __syncthreads();
    if (rl == 0) {
        float4 a = sd[0][c4];
        #pragma unroll
        for (int q = 1; q < 8; ++q) {
            float4 b = sd[q][c4];
            a.x += b.x; a.y += b.y; a.z += b.z; a.w += b.w;
        }
        atomicAdd(&gsum[c4 * 4 + 0], a.x);
        atomicAdd(&gsum[c4 * 4 + 1], a.y);
        atomicAdd(&gsum[c4 * 4 + 2], a.z);
        atomicAdd(&gsum[c4 * 4 + 3], a.w);
    }
}

__global__ void k_clf(const float* __restrict__ gsum, const float* __restrict__ W,
                      const float* __restrict__ bcls, float* __restrict__ out) {
    __shared__ float v[HC];
    int t = threadIdx.x;   // 128
    v[t] = gsum[t] * (1.f / (float)NN);
    __syncthreads();
    if (t < 2) {
        float r = 0.f;
        for (int k = 0; k < HC; ++k) r += v[k] * W[k * 2 + t];
        out[t] = r + bcls[t];
    }
}

// ---------------- launch ----------------

extern "C" void kernel_launch(void* const* d_in, const int* in_sizes, int n_in,
                              void* d_out, int out_size, void* d_ws, size_t ws_size,
                              hipStream_t stream) {
    const float* x = (const float*)d_in[0];
    const int* ei = (const int*)d_in[1];
    const float *Wl[4], *Wr[4], *att[4], *bia[4];
    for (int l = 0; l < 4; ++l) {
        Wl[l] = (const float*)d_in[2 + 4 * l];
        Wr[l] = (const float*)d_in[3 + 4 * l];
        att[l] = (const float*)d_in[4 + 4 * l];
        bia[l] = (const float*)d_in[5 + 4 * l];
    }
    const float* clfW = (const float*)d_in[18];
    const float* clfb = (const float*)d_in[19];
    float* outp = (float*)d_out;

    char* w = (char*)d_ws;
    size_t o = 0;
    auto alloc = [&](size_t bytes) {
        char* p = w + o;
        o = (o + bytes + 255) & ~(size_t)255;
        return p;
    };
    int* cnt    = (int*)alloc((size_t)NN * 4);     // also cursor
    float* gsum = (float*)alloc(HC * 4);           // adjacent to cnt: one memset covers both
    size_t zspan = o;                              // bytes from cnt to end of gsum (padded)
    int* offs  = (int*)alloc((size_t)(NN + 1) * 4);
    int* csr   = (int*)alloc((size_t)(EE + NN) * 4);
    int* bsum  = (int*)alloc((size_t)NB1 * 4);
    u16* WtAll = (u16*)alloc((size_t)WT_TOT * 2);
    u16* xb    = (u16*)alloc((size_t)NN * 256 * 2);
    u16* hb0   = (u16*)alloc((size_t)NN * HC * 2);
    u16* hb1   = (u16*)alloc((size_t)NN * HC * 2);
    float* hfin = (float*)alloc((size_t)NN * HC * 4);

    // CSR by destination + W cast
    hipMemsetAsync(cnt, 0, zspan, stream);
    k_count<<<(EE + 255) / 256, 256, 0, stream>>>(ei, cnt);
    k_bsum<<<NB1, 256, 0, stream>>>(cnt, bsum);
    k_offs<<<NB1, 256, 0, stream>>>(cnt, bsum, offs, cnt, csr);
    k_fill<<<(EE + 255) / 256, 256, 0, stream>>>(ei, cnt, csr);
    k_castw_all<<<(WT_TOT + 255) / 256, 256, 0, stream>>>(
        Wl[0], Wr[0], Wl[1], Wr[1], Wl[2], Wr[2], Wl[3], Wr[3], WtAll);

    const int GB = (NN + 127) / 128;   // 391
    const u16* Wt_l[4] = {WtAll, WtAll + WT_L0, WtAll + WT_L0 + WT_LX,
                          WtAll + WT_L0 + 2 * WT_LX};
    const u16* hb_in = nullptr;
    u16* hbb[2] = {hb0, hb1};
    for (int l = 0; l < 4; ++l) {
        if (l == 0) k_gemm<768, true ><<<GB, 512, 0, stream>>>((const void*)x, Wt_l[0], xb);
        else        k_gemm<128, false><<<GB, 512, 0, stream>>>((const void*)hb_in, Wt_l[l], xb);
        u16* ob = (l < 3) ? hbb[l & 1] : nullptr;
        float* of = (l == 3) ? hfin : nullptr;
        k_edge<<<(NN + 3) / 4, 256, 0, stream>>>(xb, att[l], bia[l], offs, csr, ob, of,
                                                 (l < 3) ? 1 : 0);
        hb_in = ob;
    }

    k_colsum<<<504, 256, 0, stream>>>(hfin, gsum);
    k_clf<<<1, 128, 0, stream>>>(gsum, clfW, clfb, outp);
}

// Round 9
// 381.642 us; speedup vs baseline: 1.2072x; 1.2072x over previous
//
#include <hip/hip_runtime.h>
#include <hip/hip_bf16.h>

#define NN 50000
#define EE 640000
#define HC 128
#define NB1 196   // ceil(NN/256)

typedef short bf16x8 __attribute__((ext_vector_type(8)));
typedef float f32x4 __attribute__((ext_vector_type(4)));
typedef unsigned short u16;

__device__ __forceinline__ u16 f2b(float f) {   // RN-even
    unsigned u = __float_as_uint(f);
    unsigned r = u + 0x7FFFu + ((u >> 16) & 1u);
    return (u16)(r >> 16);
}
__device__ __forceinline__ float b2f(u16 h) {
    return __uint_as_float(((unsigned)h) << 16);
}

__device__ __forceinline__ void gload_lds16(const void* g, void* l) {
    __builtin_amdgcn_global_load_lds((const __attribute__((address_space(1))) void*)g,
                                     (__attribute__((address_space(3))) void*)l, 16, 0, 0);
}

// sum across each 16-lane row, all lanes get result: pure DPP (no LDS op)
__device__ __forceinline__ float red16(float x) {
    x += __int_as_float(__builtin_amdgcn_update_dpp(0, __float_as_int(x), 0xB1, 0xF, 0xF, true));
    x += __int_as_float(__builtin_amdgcn_update_dpp(0, __float_as_int(x), 0x4E, 0xF, 0xF, true));
    x += __int_as_float(__builtin_amdgcn_update_dpp(0, __float_as_int(x), 0x141, 0xF, 0xF, true));
    x += __int_as_float(__builtin_amdgcn_update_dpp(0, __float_as_int(x), 0x128, 0xF, 0xF, true));
    return x;
}

// ---------------- CSR build ----------------

__global__ void k_count(const int* __restrict__ ei, int* __restrict__ cnt) {
    int e = blockIdx.x * blockDim.x + threadIdx.x;
    if (e < EE) atomicAdd(&cnt[ei[EE + e]], 1);
}

__global__ void k_bsum(const int* __restrict__ cnt, int* __restrict__ bsum) {
    __shared__ int sd[256];
    int b = blockIdx.x, t = threadIdx.x, i = b * 256 + t;
    sd[t] = (i < NN) ? cnt[i] + 1 : 0;
    __syncthreads();
    for (int o = 128; o; o >>= 1) { if (t < o) sd[t] += sd[t + o]; __syncthreads(); }
    if (!t) bsum[b] = sd[0];
}

// offs + block-scan-of-bsum + self-loop + cursor init, all fused (cursor aliases cnt)
__global__ void k_offs(const int* __restrict__ cnt_in, const int* __restrict__ bsum,
                       int* __restrict__ offs, int* __restrict__ cursor,
                       int* __restrict__ csr) {
    __shared__ int sb[256];
    __shared__ int sd[256];
    int b = blockIdx.x, t = threadIdx.x, i = b * 256 + t;
    sb[t] = (t < NB1) ? bsum[t] : 0;
    int v = (i < NN) ? cnt_in[i] + 1 : 0;
    sd[t] = v;
    __syncthreads();
    for (int o = 1; o < 256; o <<= 1) {
        int u1 = (t >= o) ? sd[t - o] : 0;
        int u2 = (t >= o) ? sb[t - o] : 0;
        __syncthreads();
        sd[t] += u1; sb[t] += u2;
        __syncthreads();
    }
    int bex = (b > 0) ? sb[b - 1] : 0;
    if (i < NN) {
        int o = bex + sd[t] - v;
        offs[i] = o;
        csr[o] = i;          // self loop first
        cursor[i] = o + 1;
    }
    if (b == NB1 - 1 && t == 0) offs[NN] = sb[NB1 - 1];
}

__global__ void k_fill(const int* __restrict__ ei, int* __restrict__ cursor,
                       int* __restrict__ csr) {
    int e = blockIdx.x * blockDim.x + threadIdx.x;
    if (e < EE) {
        int s = ei[e], d = ei[EE + e];
        int pos = atomicAdd(&cursor[d], 1);
        csr[pos] = s;
    }
}

// ---------------- all-layer W cast+transpose ----------------

#define WT_L0 196608              // 256*768
#define WT_LX 32768               // 256*128
#define WT_TOT (WT_L0 + 3 * WT_LX)

__global__ void k_castw_all(const float* __restrict__ Wl1, const float* __restrict__ Wr1,
                            const float* __restrict__ Wl2, const float* __restrict__ Wr2,
                            const float* __restrict__ Wl3, const float* __restrict__ Wr3,
                            const float* __restrict__ Wl4, const float* __restrict__ Wr4,
                            u16* __restrict__ WtAll) {
    int gid = blockIdx.x * 256 + threadIdx.x;
    if (gid >= WT_TOT) return;
    const float *Wl, *Wr;
    int idx, K, base;
    if (gid < WT_L0) { Wl = Wl1; Wr = Wr1; idx = gid; K = 768; base = 0; }
    else {
        int r = gid - WT_L0;
        int l = r >> 15; idx = r & (WT_LX - 1); K = 128; base = WT_L0 + l * WT_LX;
        if (l == 0)      { Wl = Wl2; Wr = Wr2; }
        else if (l == 1) { Wl = Wl3; Wr = Wr3; }
        else             { Wl = Wl4; Wr = Wr4; }
    }
    int c = idx / K, k = idx - c * K;
    float v = (c < 128) ? Wl[k * 128 + c] : Wr[k * 128 + (c - 128)];
    WtAll[base + idx] = f2b(v);
}

// ---------------- MFMA bf16 GEMM (measured-best structure: R6 394.5 run) ----------------
// xb[N][256] = A[N,K] @ Wt^T (bf16 out). Tile 128 rows x 256 cols, 8 waves (2x4, 64x64 each),
// BK=64, 512 threads. LDS: As[128][64] (16KB) + Bs[256][64] (32KB) = 48KB.
// 16B-chunk XOR swizzle phys = logical ^ (row&7); pre-swizzled global source, linear LDS dest.

template<int K, bool F32A>
__global__ __launch_bounds__(512, 4)
void k_gemm(const void* __restrict__ Ag, const u16* __restrict__ Wt,
            u16* __restrict__ xb) {
    __shared__ __align__(16) u16 As[128 * 64];
    __shared__ __align__(16) u16 Bs[256 * 64];
    const int tid = threadIdx.x;
    const int wv = tid >> 6, ln = tid & 63;
    const int wr = wv >> 2, wc = wv & 3;
    const int m0 = blockIdx.x * 128;
    const int lrow = ln & 15, g = ln >> 4;

    f32x4 acc[4][4] = {};

    const float* Af = (const float*)Ag;
    const u16* Ab = (const u16*)Ag;
    const int arow = tid >> 2, aq = tid & 3;   // 512 thr -> arow 0..127
    int arg = m0 + arow; if (arg >= NN) arg = 0;
    float4 ra0, ra1, ra2, ra3;

    if constexpr (F32A) {
        const float* src = Af + (size_t)arg * K + aq * 16;
        ra0 = *(const float4*)(src);
        ra1 = *(const float4*)(src + 4);
        ra2 = *(const float4*)(src + 8);
        ra3 = *(const float4*)(src + 12);
    }

    constexpr int NSTEP = K / 64;
    for (int ks = 0; ks < NSTEP; ++ks) {
        if constexpr (F32A) {
            const int s = arow & 7;
            bf16x8 v0, v1;
            v0[0] = (short)f2b(ra0.x); v0[1] = (short)f2b(ra0.y);
            v0[2] = (short)f2b(ra0.z); v0[3] = (short)f2b(ra0.w);
            v0[4] = (short)f2b(ra1.x); v0[5] = (short)f2b(ra1.y);
            v0[6] = (short)f2b(ra1.z); v0[7] = (short)f2b(ra1.w);
            v1[0] = (short)f2b(ra2.x); v1[1] = (short)f2b(ra2.y);
            v1[2] = (short)f2b(ra2.z); v1[3] = (short)f2b(ra2.w);
            v1[4] = (short)f2b(ra3.x); v1[5] = (short)f2b(ra3.y);
            v1[6] = (short)f2b(ra3.z); v1[7] = (short)f2b(ra3.w);
            *(bf16x8*)&As[arow * 64 + (((aq * 2) ^ s) * 8)] = v0;
            *(bf16x8*)&As[arow * 64 + (((aq * 2 + 1) ^ s) * 8)] = v1;
        } else {
            #pragma unroll
            for (int q = 0; q < 2; ++q) {
                int r8 = (wv * 2 + q) * 8;          // 16 segs x 8 rows = 128
                int row = r8 + (ln >> 3);
                int lc = (ln & 7) ^ (row & 7);
                int rg = m0 + row; if (rg >= NN) rg = 0;
                gload_lds16(Ab + (size_t)rg * K + ks * 64 + lc * 8, &As[r8 * 64]);
            }
        }
        #pragma unroll
        for (int q = 0; q < 4; ++q) {
            int r8 = (wv * 4 + q) * 8;              // 32 segs x 8 rows = 256
            int row = r8 + (ln >> 3);
            int lc = (ln & 7) ^ (row & 7);
            gload_lds16(Wt + (size_t)row * K + ks * 64 + lc * 8, &Bs[r8 * 64]);
        }
        __syncthreads();   // drains vmcnt (gload_lds) + lgkmcnt (ds_write)

        if constexpr (F32A) {
            if (ks + 1 < NSTEP) {   // T14: issue next tile's loads, consume after next barrier
                const float* src = Af + (size_t)arg * K + (ks + 1) * 64 + aq * 16;
                ra0 = *(const float4*)(src);
                ra1 = *(const float4*)(src + 4);
                ra2 = *(const float4*)(src + 8);
                ra3 = *(const float4*)(src + 12);
            }
        }

        #pragma unroll
        for (int kk = 0; kk < 2; ++kk) {
            bf16x8 af[4], bfr[4];
            #pragma unroll
            for (int f = 0; f < 4; ++f) {
                int r = wr * 64 + f * 16 + lrow;
                af[f] = *(const bf16x8*)&As[r * 64 + (((kk * 4 + g) ^ (r & 7)) * 8)];
                int c = wc * 64 + f * 16 + lrow;
                bfr[f] = *(const bf16x8*)&Bs[c * 64 + (((kk * 4 + g) ^ (c & 7)) * 8)];
            }
            #pragma unroll
            for (int i = 0; i < 4; ++i)
                #pragma unroll
                for (int j = 0; j < 4; ++j)
                    acc[i][j] = __builtin_amdgcn_mfma_f32_16x16x32_bf16(af[i], bfr[j], acc[i][j], 0, 0, 0);
        }
        __syncthreads();
    }

    const int crow0 = m0 + wr * 64 + (g << 2);
    const int ccol0 = wc * 64 + lrow;
    #pragma unroll
    for (int i = 0; i < 4; ++i)
        #pragma unroll
        for (int rr = 0; rr < 4; ++rr) {
            int row = crow0 + i * 16 + rr;
            if (row < NN) {
                #pragma unroll
                for (int j = 0; j < 4; ++j)
                    xb[(size_t)row * 256 + ccol0 + j * 16] = f2b(acc[i][j][rr]);
            }
        }
}

// ---------------- per-node online-softmax GATv2 aggregation ----------------
// Measured-best edge variant (R7 bench, 388.8 run): ONE WAVE per node; lane ln owns
// channel pair ch0 = (ln>>4)*32 + (ln&15)*2. Indices loaded 64-wide coalesced,
// broadcast via __shfl; 4 independent gather/softmax streams; single-exp online update.

__global__ __launch_bounds__(256)
void k_edge(const u16* __restrict__ xb, const float* __restrict__ att,
            const float* __restrict__ bias, const int* __restrict__ offs,
            const int* __restrict__ csr, u16* __restrict__ outb,
            float* __restrict__ outf, int relu) {
    int i = blockIdx.x * 4 + (threadIdx.x >> 6);
    if (i >= NN) return;
    int ln = threadIdx.x & 63;
    int ch0 = ((ln >> 4) << 5) + ((ln & 15) << 1);

    unsigned xr2 = *(const unsigned*)&xb[(size_t)i * 256 + 128 + ch0];
    float xri0 = b2f((u16)xr2), xri1 = b2f((u16)(xr2 >> 16));
    float2 atv = *(const float2*)&att[ch0];
    const float at0 = atv.x, at1 = atv.y;
    int beg = offs[i];
    int deg = offs[i + 1] - beg;

    float m0v = -3.0e38f, s0v = 0.f, p00 = 0.f, p01 = 0.f;
    float m1v = -3.0e38f, s1v = 0.f, p10 = 0.f, p11 = 0.f;
    float m2v = -3.0e38f, s2v = 0.f, p20 = 0.f, p21 = 0.f;
    float m3v = -3.0e38f, s3v = 0.f, p30 = 0.f, p31 = 0.f;

#define GATH(k, jj) unsigned w##k = *(const unsigned*)&xb[(size_t)(jj) * 256 + ch0];
#define UPD(k, M, S, A0, A1) { \
    float v0 = b2f((u16)w##k), v1 = b2f((u16)(w##k >> 16)); \
    float u0 = v0 + xri0; u0 = fmaxf(u0, 0.2f * u0); \
    float u1 = v1 + xri1; u1 = fmaxf(u1, 0.2f * u1); \
    float e = red16(u0 * at0 + u1 * at1); \
    float d = e - M; \
    float tt = __expf(-fabsf(d)); \
    bool ng = (d <= 0.f); \
    float c = ng ? 1.f : tt; \
    float ww = ng ? tt : 1.f; \
    M = ng ? M : e; \
    S = S * c + ww; A0 = A0 * c + ww * v0; A1 = A1 * c + ww * v1; }

    for (int base = 0; base < deg; base += 64) {
        int lim = deg - base; if (lim > 64) lim = 64;
        int idxv = (base + ln < deg) ? csr[beg + base + ln] : 0;
        int p = 0;
        for (; p + 4 <= lim; p += 4) {
            int j0 = __shfl(idxv, p);
            int j1 = __shfl(idxv, p + 1);
            int j2 = __shfl(idxv, p + 2);
            int j3 = __shfl(idxv, p + 3);
            GATH(0, j0) GATH(1, j1) GATH(2, j2) GATH(3, j3)
            UPD(0, m0v, s0v, p00, p01)
            UPD(1, m1v, s1v, p10, p11)
            UPD(2, m2v, s2v, p20, p21)
            UPD(3, m3v, s3v, p30, p31)
        }
        for (; p < lim; ++p) {
            int j0 = __shfl(idxv, p);
            GATH(4, j0)
            UPD(4, m0v, s0v, p00, p01)
        }
    }
#undef GATH
#undef UPD

    float mm = fmaxf(fmaxf(m0v, m1v), fmaxf(m2v, m3v));
    float c0 = __expf(m0v - mm), c1 = __expf(m1v - mm);
    float c2 = __expf(m2v - mm), c3 = __expf(m3v - mm);
    float s = s0v * c0 + s1v * c1 + s2v * c2 + s3v * c3 + 1e-16f;
    float inv = 1.f / s;
    float2 bv = *(const float2*)&bias[ch0];
    float o0 = (p00 * c0 + p10 * c1 + p20 * c2 + p30 * c3) * inv + bv.x;
    float o1 = (p01 * c0 + p11 * c1 + p21 * c2 + p31 * c3) * inv + bv.y;
    if (relu) { o0 = fmaxf(o0, 0.f); o1 = fmaxf(o1, 0.f); }
    if (outb) {
        unsigned pk = (unsigned)f2b(o0) | ((unsigned)f2b(o1) << 16);
        *(unsigned*)&outb[(size_t)i * HC + ch0] = pk;
    }
    if (outf) {
        *(float2*)&outf[(size_t)i * HC + ch0] = make_float2(o0, o1);
    }
}

// ---------------- tail ----------------

__global__ __launch_bounds__(256)
void k_colsum(const float* __restrict__ h, float* __restrict__ gsum) {
    __shared__ float4 sd[8][32];
    int t = threadIdx.x;
    int c4 = t & 31, rl = t >> 5;
    float sx = 0.f, sy = 0.f, sz = 0.f, sw = 0.f;
    for (int r = blockIdx.x * 8 + rl; r < NN; r += 8 * gridDim.x) {
        float4 v = *(const float4*)&h[(size_t)r * HC + c4 * 4];
        sx += v.x; sy += v.y; sz += v.z; sw += v.w;
    }
    sd[rl][c4] = make_float4(sx, sy, sz, sw);
    __syncthreads();
    if (rl == 0) {
        float4 a = sd[0][c4];
        #pragma unroll
        for (int q = 1; q < 8; ++q) {
            float4 b = sd[q][c4];
            a.x += b.x; a.y += b.y; a.z += b.z; a.w += b.w;
        }
        atomicAdd(&gsum[c4 * 4 + 0], a.x);
        atomicAdd(&gsum[c4 * 4 + 1], a.y);
        atomicAdd(&gsum[c4 * 4 + 2], a.z);
        atomicAdd(&gsum[c4 * 4 + 3], a.w);
    }
}

__global__ void k_clf(const float* __restrict__ gsum, const float* __restrict__ W,
                      const float* __restrict__ bcls, float* __restrict__ out) {
    __shared__ float v[HC];
    int t = threadIdx.x;   // 128
    v[t] = gsum[t] * (1.f / (float)NN);
    __syncthreads();
    if (t < 2) {
        float r = 0.f;
        for (int k = 0; k < HC; ++k) r += v[k] * W[k * 2 + t];
        out[t] = r + bcls[t];
    }
}

// ---------------- launch ----------------

extern "C" void kernel_launch(void* const* d_in, const int* in_sizes, int n_in,
                              void* d_out, int out_size, void* d_ws, size_t ws_size,
                              hipStream_t stream) {
    const float* x = (const float*)d_in[0];
    const int* ei = (const int*)d_in[1];
    const float *Wl[4], *Wr[4], *att[4], *bia[4];
    for (int l = 0; l < 4; ++l) {
        Wl[l] = (const float*)d_in[2 + 4 * l];
        Wr[l] = (const float*)d_in[3 + 4 * l];
        att[l] = (const float*)d_in[4 + 4 * l];
        bia[l] = (const float*)d_in[5 + 4 * l];
    }
    const float* clfW = (const float*)d_in[18];
    const float* clfb = (const float*)d_in[19];
    float* outp = (float*)d_out;

    char* w = (char*)d_ws;
    size_t o = 0;
    auto alloc = [&](size_t bytes) {
        char* p = w + o;
        o = (o + bytes + 255) & ~(size_t)255;
        return p;
    };
    int* cnt    = (int*)alloc((size_t)NN * 4);     // also cursor
    float* gsum = (float*)alloc(HC * 4);           // adjacent to cnt: one memset covers both
    size_t zspan = o;                              // bytes from cnt to end of gsum (padded)
    int* offs  = (int*)alloc((size_t)(NN + 1) * 4);
    int* csr   = (int*)alloc((size_t)(EE + NN) * 4);
    int* bsum  = (int*)alloc((size_t)NB1 * 4);
    u16* WtAll = (u16*)alloc((size_t)WT_TOT * 2);
    u16* xb    = (u16*)alloc((size_t)NN * 256 * 2);
    u16* hb0   = (u16*)alloc((size_t)NN * HC * 2);
    u16* hb1   = (u16*)alloc((size_t)NN * HC * 2);
    float* hfin = (float*)alloc((size_t)NN * HC * 4);

    // CSR by destination + W cast
    hipMemsetAsync(cnt, 0, zspan, stream);
    k_count<<<(EE + 255) / 256, 256, 0, stream>>>(ei, cnt);
    k_bsum<<<NB1, 256, 0, stream>>>(cnt, bsum);
    k_offs<<<NB1, 256, 0, stream>>>(cnt, bsum, offs, cnt, csr);
    k_fill<<<(EE + 255) / 256, 256, 0, stream>>>(ei, cnt, csr);
    k_castw_all<<<(WT_TOT + 255) / 256, 256, 0, stream>>>(
        Wl[0], Wr[0], Wl[1], Wr[1], Wl[2], Wr[2], Wl[3], Wr[3], WtAll);

    const int GB = (NN + 127) / 128;   // 391
    const u16* Wt_l[4] = {WtAll, WtAll + WT_L0, WtAll + WT_L0 + WT_LX,
                          WtAll + WT_L0 + 2 * WT_LX};
    const u16* hb_in = nullptr;
    u16* hbb[2] = {hb0, hb1};
    for (int l = 0; l < 4; ++l) {
        if (l == 0) k_gemm<768, true ><<<GB, 512, 0, stream>>>((const void*)x, Wt_l[0], xb);
        else        k_gemm<128, false><<<GB, 512, 0, stream>>>((const void*)hb_in, Wt_l[l], xb);
        u16* ob = (l < 3) ? hbb[l & 1] : nullptr;
        float* of = (l == 3) ? hfin : nullptr;
        k_edge<<<(NN + 3) / 4, 256, 0, stream>>>(xb, att[l], bia[l], offs, csr, ob, of,
                                                 (l < 3) ? 1 : 0);
        hb_in = ob;
    }

    k_colsum<<<504, 256, 0, stream>>>(hfin, gsum);
    k_clf<<<1, 128, 0, stream>>>(gsum, clfW, clfb, outp);
}

// Round 10
// 364.771 us; speedup vs baseline: 1.2630x; 1.0462x over previous
//
#include <hip/hip_runtime.h>
#include <hip/hip_bf16.h>
#include <hip/hip_fp16.h>

#define NN 50000
#define EE 640000
#define HC 128
#define NB1 196   // ceil(NN/256)

typedef _Float16 f16x8 __attribute__((ext_vector_type(8)));
typedef _Float16 h2 __attribute__((ext_vector_type(2)));
typedef float f32x4 __attribute__((ext_vector_type(4)));
typedef unsigned short u16;

__device__ __forceinline__ u16 f2h(float f) {
    return __builtin_bit_cast(u16, (_Float16)f);
}
__device__ __forceinline__ h2 bch2(unsigned a) { return __builtin_bit_cast(h2, a); }
__device__ __forceinline__ h2 habs2(h2 a) {
    return __builtin_bit_cast(h2, __builtin_bit_cast(unsigned, a) & 0x7FFF7FFFu);
}

__device__ __forceinline__ void gload_lds16(const void* g, void* l) {
    __builtin_amdgcn_global_load_lds((const __attribute__((address_space(1))) void*)g,
                                     (__attribute__((address_space(3))) void*)l, 16, 0, 0);
}

// sum across each 8-lane group (all 8 lanes get result): DPP xor1, xor2 + ds_swizzle xor4
__device__ __forceinline__ float red8(float x) {
    x += __int_as_float(__builtin_amdgcn_update_dpp(0, __float_as_int(x), 0xB1, 0xF, 0xF, true));
    x += __int_as_float(__builtin_amdgcn_update_dpp(0, __float_as_int(x), 0x4E, 0xF, 0xF, true));
    x += __int_as_float(__builtin_amdgcn_ds_swizzle(__float_as_int(x), 0x101F));
    return x;
}

// ---------------- CSR build ----------------

__global__ void k_count(const int* __restrict__ ei, int* __restrict__ cnt) {
    int e = blockIdx.x * blockDim.x + threadIdx.x;
    if (e < EE) atomicAdd(&cnt[ei[EE + e]], 1);
}

__global__ void k_bsum(const int* __restrict__ cnt, int* __restrict__ bsum) {
    __shared__ int sd[256];
    int b = blockIdx.x, t = threadIdx.x, i = b * 256 + t;
    sd[t] = (i < NN) ? cnt[i] + 1 : 0;
    __syncthreads();
    for (int o = 128; o; o >>= 1) { if (t < o) sd[t] += sd[t + o]; __syncthreads(); }
    if (!t) bsum[b] = sd[0];
}

// offs + block-scan-of-bsum + self-loop + cursor init, all fused (cursor aliases cnt)
__global__ void k_offs(const int* __restrict__ cnt_in, const int* __restrict__ bsum,
                       int* __restrict__ offs, int* __restrict__ cursor,
                       int* __restrict__ csr) {
    __shared__ int sb[256];
    __shared__ int sd[256];
    int b = blockIdx.x, t = threadIdx.x, i = b * 256 + t;
    sb[t] = (t < NB1) ? bsum[t] : 0;
    int v = (i < NN) ? cnt_in[i] + 1 : 0;
    sd[t] = v;
    __syncthreads();
    for (int o = 1; o < 256; o <<= 1) {
        int u1 = (t >= o) ? sd[t - o] : 0;
        int u2 = (t >= o) ? sb[t - o] : 0;
        __syncthreads();
        sd[t] += u1; sb[t] += u2;
        __syncthreads();
    }
    int bex = (b > 0) ? sb[b - 1] : 0;
    if (i < NN) {
        int o = bex + sd[t] - v;
        offs[i] = o;
        csr[o] = i;          // self loop first
        cursor[i] = o + 1;
    }
    if (b == NB1 - 1 && t == 0) offs[NN] = sb[NB1 - 1];
}

__global__ void k_fill(const int* __restrict__ ei, int* __restrict__ cursor,
                       int* __restrict__ csr) {
    int e = blockIdx.x * blockDim.x + threadIdx.x;
    if (e < EE) {
        int s = ei[e], d = ei[EE + e];
        int pos = atomicAdd(&cursor[d], 1);
        csr[pos] = s;
    }
}

// ---------------- all-layer W cast+transpose (fp16) ----------------

#define WT_L0 196608              // 256*768
#define WT_LX 32768               // 256*128
#define WT_TOT (WT_L0 + 3 * WT_LX)

__global__ void k_castw_all(const float* __restrict__ Wl1, const float* __restrict__ Wr1,
                            const float* __restrict__ Wl2, const float* __restrict__ Wr2,
                            const float* __restrict__ Wl3, const float* __restrict__ Wr3,
                            const float* __restrict__ Wl4, const float* __restrict__ Wr4,
                            u16* __restrict__ WtAll) {
    int gid = blockIdx.x * 256 + threadIdx.x;
    if (gid >= WT_TOT) return;
    const float *Wl, *Wr;
    int idx, K, base;
    if (gid < WT_L0) { Wl = Wl1; Wr = Wr1; idx = gid; K = 768; base = 0; }
    else {
        int r = gid - WT_L0;
        int l = r >> 15; idx = r & (WT_LX - 1); K = 128; base = WT_L0 + l * WT_LX;
        if (l == 0)      { Wl = Wl2; Wr = Wr2; }
        else if (l == 1) { Wl = Wl3; Wr = Wr3; }
        else             { Wl = Wl4; Wr = Wr4; }
    }
    int c = idx / K, k = idx - c * K;
    float v = (c < 128) ? Wl[k * 128 + c] : Wr[k * 128 + (c - 128)];
    WtAll[base + idx] = f2h(v);
}

// ---------------- MFMA fp16 GEMM (measured-best structure; dtype bf16->f16) ----------------
// xb[N][256] = A[N,K] @ Wt^T (f16 out). Tile 128 rows x 256 cols, 8 waves (2x4, 64x64 each),
// BK=64, 512 threads. LDS: As[128][64] (16KB) + Bs[256][64] (32KB) = 48KB.
// 16B-chunk XOR swizzle phys = logical ^ (row&7); pre-swizzled global source, linear LDS dest.

template<int K, bool F32A>
__global__ __launch_bounds__(512, 4)
void k_gemm(const void* __restrict__ Ag, const u16* __restrict__ Wt,
            u16* __restrict__ xb) {
    __shared__ __align__(16) u16 As[128 * 64];
    __shared__ __align__(16) u16 Bs[256 * 64];
    const int tid = threadIdx.x;
    const int wv = tid >> 6, ln = tid & 63;
    const int wr = wv >> 2, wc = wv & 3;
    const int m0 = blockIdx.x * 128;
    const int lrow = ln & 15, g = ln >> 4;

    f32x4 acc[4][4] = {};

    const float* Af = (const float*)Ag;
    const u16* Ab = (const u16*)Ag;
    const int arow = tid >> 2, aq = tid & 3;   // 512 thr -> arow 0..127
    int arg = m0 + arow; if (arg >= NN) arg = 0;
    float4 ra0, ra1, ra2, ra3;

    if constexpr (F32A) {
        const float* src = Af + (size_t)arg * K + aq * 16;
        ra0 = *(const float4*)(src);
        ra1 = *(const float4*)(src + 4);
        ra2 = *(const float4*)(src + 8);
        ra3 = *(const float4*)(src + 12);
    }

    constexpr int NSTEP = K / 64;
    for (int ks = 0; ks < NSTEP; ++ks) {
        if constexpr (F32A) {
            const int s = arow & 7;
            f16x8 v0, v1;
            v0[0] = (_Float16)ra0.x; v0[1] = (_Float16)ra0.y;
            v0[2] = (_Float16)ra0.z; v0[3] = (_Float16)ra0.w;
            v0[4] = (_Float16)ra1.x; v0[5] = (_Float16)ra1.y;
            v0[6] = (_Float16)ra1.z; v0[7] = (_Float16)ra1.w;
            v1[0] = (_Float16)ra2.x; v1[1] = (_Float16)ra2.y;
            v1[2] = (_Float16)ra2.z; v1[3] = (_Float16)ra2.w;
            v1[4] = (_Float16)ra3.x; v1[5] = (_Float16)ra3.y;
            v1[6] = (_Float16)ra3.z; v1[7] = (_Float16)ra3.w;
            *(f16x8*)&As[arow * 64 + (((aq * 2) ^ s) * 8)] = v0;
            *(f16x8*)&As[arow * 64 + (((aq * 2 + 1) ^ s) * 8)] = v1;
        } else {
            #pragma unroll
            for (int q = 0; q < 2; ++q) {
                int r8 = (wv * 2 + q) * 8;          // 16 segs x 8 rows = 128
                int row = r8 + (ln >> 3);
                int lc = (ln & 7) ^ (row & 7);
                int rg = m0 + row; if (rg >= NN) rg = 0;
                gload_lds16(Ab + (size_t)rg * K + ks * 64 + lc * 8, &As[r8 * 64]);
            }
        }
        #pragma unroll
        for (int q = 0; q < 4; ++q) {
            int r8 = (wv * 4 + q) * 8;              // 32 segs x 8 rows = 256
            int row = r8 + (ln >> 3);
            int lc = (ln & 7) ^ (row & 7);
            gload_lds16(Wt + (size_t)row * K + ks * 64 + lc * 8, &Bs[r8 * 64]);
        }
        __syncthreads();   // drains vmcnt (gload_lds) + lgkmcnt (ds_write)

        if constexpr (F32A) {
            if (ks + 1 < NSTEP) {   // T14: issue next tile's loads, consume after next barrier
                const float* src = Af + (size_t)arg * K + (ks + 1) * 64 + aq * 16;
                ra0 = *(const float4*)(src);
                ra1 = *(const float4*)(src + 4);
                ra2 = *(const float4*)(src + 8);
                ra3 = *(const float4*)(src + 12);
            }
        }

        #pragma unroll
        for (int kk = 0; kk < 2; ++kk) {
            f16x8 af[4], bfr[4];
            #pragma unroll
            for (int f = 0; f < 4; ++f) {
                int r = wr * 64 + f * 16 + lrow;
                af[f] = *(const f16x8*)&As[r * 64 + (((kk * 4 + g) ^ (r & 7)) * 8)];
                int c = wc * 64 + f * 16 + lrow;
                bfr[f] = *(const f16x8*)&Bs[c * 64 + (((kk * 4 + g) ^ (c & 7)) * 8)];
            }
            #pragma unroll
            for (int i = 0; i < 4; ++i)
                #pragma unroll
                for (int j = 0; j < 4; ++j)
                    acc[i][j] = __builtin_amdgcn_mfma_f32_16x16x32_f16(af[i], bfr[j], acc[i][j], 0, 0, 0);
        }
        __syncthreads();
    }

    const int crow0 = m0 + wr * 64 + (g << 2);
    const int ccol0 = wc * 64 + lrow;
    #pragma unroll
    for (int i = 0; i < 4; ++i)
        #pragma unroll
        for (int rr = 0; rr < 4; ++rr) {
            int row = crow0 + i * 16 + rr;
            if (row < NN) {
                #pragma unroll
                for (int j = 0; j < 4; ++j)
                    xb[(size_t)row * 256 + ccol0 + j * 16] = f2h(acc[i][j][rr]);
            }
        }
}

// ---------------- per-node online-softmax GATv2 aggregation (fp16 packed, 2 nodes/wave) ----
// Half-wave (32 lanes) per node: lane lh owns channels c4 = lh*4 (2 h2 pairs, 8B gather).
// Logit: pk_add + leaky(0.6u+0.4|u|) + v_dot2_f32_f16, reduce over 8 lanes/head (red8).
// 4 independent gather/softmax streams; single-exp predicated online update.

__global__ __launch_bounds__(256)
void k_edge(const u16* __restrict__ xb, const float* __restrict__ att,
            const float* __restrict__ bias, const int* __restrict__ offs,
            const int* __restrict__ csr, u16* __restrict__ outb,
            float* __restrict__ outf, int relu) {
    const int wv = threadIdx.x >> 6;
    const int ln = threadIdx.x & 63;
    const int half = ln >> 5, lh = ln & 31;
    const int i = blockIdx.x * 8 + wv * 2 + half;   // grid 6250 -> i < 50000 always
    const int c4 = lh * 4;

    uint2 xrw = *(const uint2*)&xb[(size_t)i * 256 + 128 + c4];
    const h2 xr01 = bch2(xrw.x), xr23 = bch2(xrw.y);
    float4 av = *(const float4*)&att[c4];
    const h2 at01 = {(_Float16)av.x, (_Float16)av.y};
    const h2 at23 = {(_Float16)av.z, (_Float16)av.w};
    const h2 C06 = {(_Float16)0.6f, (_Float16)0.6f};
    const h2 C04 = {(_Float16)0.4f, (_Float16)0.4f};

    int beg = offs[i];
    int deg = offs[i + 1] - beg;
    int degO = __shfl_xor(deg, 32);
    int degM = (deg > degO) ? deg : degO;          // wave-uniform

    float m0v = -3.0e38f, s0v = 0.f, a00 = 0.f, a01 = 0.f, a02 = 0.f, a03 = 0.f;
    float m1v = -3.0e38f, s1v = 0.f, a10 = 0.f, a11 = 0.f, a12 = 0.f, a13 = 0.f;
    float m2v = -3.0e38f, s2v = 0.f, a20 = 0.f, a21 = 0.f, a22 = 0.f, a23 = 0.f;
    float m3v = -3.0e38f, s3v = 0.f, a30 = 0.f, a31 = 0.f, a32 = 0.f, a33 = 0.f;

#define GATH(k, jj) uint2 w##k = *(const uint2*)&xb[(size_t)(jj) * 256 + c4];
#define UPD(k, M, S, A0, A1, A2, A3, ok) { \
    h2 v01 = bch2(w##k.x), v23 = bch2(w##k.y); \
    h2 u01 = v01 + xr01, u23 = v23 + xr23; \
    h2 l01 = u01 * C06 + habs2(u01) * C04; \
    h2 l23 = u23 * C06 + habs2(u23) * C04; \
    float e = __builtin_amdgcn_fdot2(l01, at01, \
              __builtin_amdgcn_fdot2(l23, at23, 0.f, false), false); \
    e = red8(e); \
    float d = e - M; \
    float tt = __expf(-fabsf(d)); \
    bool ng = (d <= 0.f) || (!(ok)); \
    float c = ng ? 1.f : tt; \
    float ww = (ok) ? (ng ? tt : 1.f) : 0.f; \
    M = ng ? M : e; \
    S = S * c + ww; \
    A0 = A0 * c + ww * (float)v01[0]; A1 = A1 * c + ww * (float)v01[1]; \
    A2 = A2 * c + ww * (float)v23[0]; A3 = A3 * c + ww * (float)v23[1]; }

    for (int base = 0; base < degM; base += 32) {
        int idxv = (base + lh < deg) ? csr[beg + base + lh] : i;
        int lim = degM - base; if (lim > 32) lim = 32;   // wave-uniform
        int myl = deg - base;                            // per-half remaining
        for (int p = 0; p < lim; p += 4) {
            int j0 = __shfl(idxv, p + 0, 32);
            int j1 = __shfl(idxv, p + 1, 32);
            int j2 = __shfl(idxv, p + 2, 32);
            int j3 = __shfl(idxv, p + 3, 32);
            GATH(0, j0) GATH(1, j1) GATH(2, j2) GATH(3, j3)
            UPD(0, m0v, s0v, a00, a01, a02, a03, (p + 0 < myl))
            UPD(1, m1v, s1v, a10, a11, a12, a13, (p + 1 < myl))
            UPD(2, m2v, s2v, a20, a21, a22, a23, (p + 2 < myl))
            UPD(3, m3v, s3v, a30, a31, a32, a33, (p + 3 < myl))
        }
    }
#undef GATH
#undef UPD

    float mm = fmaxf(fmaxf(m0v, m1v), fmaxf(m2v, m3v));
    float c0 = __expf(m0v - mm), c1 = __expf(m1v - mm);
    float c2 = __expf(m2v - mm), c3 = __expf(m3v - mm);
    float s = s0v * c0 + s1v * c1 + s2v * c2 + s3v * c3 + 1e-16f;
    float inv = 1.f / s;
    float4 bv = *(const float4*)&bias[c4];
    float o0 = (a00 * c0 + a10 * c1 + a20 * c2 + a30 * c3) * inv + bv.x;
    float o1 = (a01 * c0 + a11 * c1 + a21 * c2 + a31 * c3) * inv + bv.y;
    float o2 = (a02 * c0 + a12 * c1 + a22 * c2 + a32 * c3) * inv + bv.z;
    float o3 = (a03 * c0 + a13 * c1 + a23 * c2 + a33 * c3) * inv + bv.w;
    if (relu) {
        o0 = fmaxf(o0, 0.f); o1 = fmaxf(o1, 0.f);
        o2 = fmaxf(o2, 0.f); o3 = fmaxf(o3, 0.f);
    }
    if (outb) {
        uint2 pk;
        pk.x = (unsigned)f2h(o0) | ((unsigned)f2h(o1) << 16);
        pk.y = (unsigned)f2h(o2) | ((unsigned)f2h(o3) << 16);
        *(uint2*)&outb[(size_t)i * HC + c4] = pk;
    }
    if (outf) {
        *(float4*)&outf[(size_t)i * HC + c4] = make_float4(o0, o1, o2, o3);
    }
}

// ---------------- tail ----------------

__global__ __launch_bounds__(256)
void k_colsum(const float* __restrict__ h, float* __restrict__ gsum) {
    __shared__ float4 sd[8][32];
    int t = threadIdx.x;
    int c4 = t & 31, rl = t >> 5;
    float sx = 0.f, sy = 0.f, sz = 0.f, sw = 0.f;
    for (int r = blockIdx.x * 8 + rl; r < NN; r += 8 * gridDim.x) {
        float4 v = *(const float4*)&h[(size_t)r * HC + c4 * 4];
        sx += v.x; sy += v.y; sz += v.z; sw += v.w;
    }
    sd[rl][c4] = make_float4(sx, sy, sz, sw);
    __syncthreads();
    if (rl == 0) {
        float4 a = sd[0][c4];
        #pragma unroll
        for (int q = 1; q < 8; ++q) {
            float4 b = sd[q][c4];
            a.x += b.x; a.y += b.y; a.z += b.z; a.w += b.w;
        }
        atomicAdd(&gsum[c4 * 4 + 0], a.x);
        atomicAdd(&gsum[c4 * 4 + 1], a.y);
        atomicAdd(&gsum[c4 * 4 + 2], a.z);
        atomicAdd(&gsum[c4 * 4 + 3], a.w);
    }
}

__global__ void k_clf(const float* __restrict__ gsum, const float* __restrict__ W,
                      const float* __restrict__ bcls, float* __restrict__ out) {
    __shared__ float v[HC];
    int t = threadIdx.x;   // 128
    v[t] = gsum[t] * (1.f / (float)NN);
    __syncthreads();
    if (t < 2) {
        float r = 0.f;
        for (int k = 0; k < HC; ++k) r += v[k] * W[k * 2 + t];
        out[t] = r + bcls[t];
    }
}

// ---------------- launch ----------------

extern "C" void kernel_launch(void* const* d_in, const int* in_sizes, int n_in,
                              void* d_out, int out_size, void* d_ws, size_t ws_size,
                              hipStream_t stream) {
    const float* x = (const float*)d_in[0];
    const int* ei = (const int*)d_in[1];
    const float *Wl[4], *Wr[4], *att[4], *bia[4];
    for (int l = 0; l < 4; ++l) {
        Wl[l] = (const float*)d_in[2 + 4 * l];
        Wr[l] = (const float*)d_in[3 + 4 * l];
        att[l] = (const float*)d_in[4 + 4 * l];
        bia[l] = (const float*)d_in[5 + 4 * l];
    }
    const float* clfW = (const float*)d_in[18];
    const float* clfb = (const float*)d_in[19];
    float* outp = (float*)d_out;

    char* w = (char*)d_ws;
    size_t o = 0;
    auto alloc = [&](size_t bytes) {
        char* p = w + o;
        o = (o + bytes + 255) & ~(size_t)255;
        return p;
    };
    int* cnt    = (int*)alloc((size_t)NN * 4);     // also cursor
    float* gsum = (float*)alloc(HC * 4);           // adjacent to cnt: one memset covers both
    size_t zspan = o;                              // bytes from cnt to end of gsum (padded)
    int* offs  = (int*)alloc((size_t)(NN + 1) * 4);
    int* csr   = (int*)alloc((size_t)(EE + NN) * 4);
    int* bsum  = (int*)alloc((size_t)NB1 * 4);
    u16* WtAll = (u16*)alloc((size_t)WT_TOT * 2);
    u16* xb    = (u16*)alloc((size_t)NN * 256 * 2);
    u16* hb0   = (u16*)alloc((size_t)NN * HC * 2);
    u16* hb1   = (u16*)alloc((size_t)NN * HC * 2);
    float* hfin = (float*)alloc((size_t)NN * HC * 4);

    // CSR by destination + W cast
    hipMemsetAsync(cnt, 0, zspan, stream);
    k_count<<<(EE + 255) / 256, 256, 0, stream>>>(ei, cnt);
    k_bsum<<<NB1, 256, 0, stream>>>(cnt, bsum);
    k_offs<<<NB1, 256, 0, stream>>>(cnt, bsum, offs, cnt, csr);
    k_fill<<<(EE + 255) / 256, 256, 0, stream>>>(ei, cnt, csr);
    k_castw_all<<<(WT_TOT + 255) / 256, 256, 0, stream>>>(
        Wl[0], Wr[0], Wl[1], Wr[1], Wl[2], Wr[2], Wl[3], Wr[3], WtAll);

    const int GB = (NN + 127) / 128;   // 391
    const u16* Wt_l[4] = {WtAll, WtAll + WT_L0, WtAll + WT_L0 + WT_LX,
                          WtAll + WT_L0 + 2 * WT_LX};
    const u16* hb_in = nullptr;
    u16* hbb[2] = {hb0, hb1};
    for (int l = 0; l < 4; ++l) {
        if (l == 0) k_gemm<768, true ><<<GB, 512, 0, stream>>>((const void*)x, Wt_l[0], xb);
        else        k_gemm<128, false><<<GB, 512, 0, stream>>>((const void*)hb_in, Wt_l[l], xb);
        u16* ob = (l < 3) ? hbb[l & 1] : nullptr;
        float* of = (l == 3) ? hfin : nullptr;
        k_edge<<<NN / 8, 256, 0, stream>>>(xb, att[l], bia[l], offs, csr, ob, of,
                                           (l < 3) ? 1 : 0);
        hb_in = ob;
    }

    k_colsum<<<504, 256, 0, stream>>>(hfin, gsum);
    k_clf<<<1, 128, 0, stream>>>(gsum, clfW, clfb, outp);
}